// Round 1
// baseline (105.618 us; speedup 1.0000x reference)
//
#include <hip/hip_runtime.h>

// Per-channel (row) asymmetric min-max fake quantization.
// x: [C=4096, N=16384] fp32. One block per row; data held in registers
// between the min/max pass and the quantize pass (single HBM read).

constexpr int N_COLS = 16384;
constexpr int THREADS = 512;                       // 8 waves
constexpr int N_WAVES = THREADS / 64;
constexpr int VPT = N_COLS / 4 / THREADS;          // float4 per thread = 8
constexpr float LEVELS_F = 255.0f;
constexpr float EPS = 1e-8f;

__global__ __launch_bounds__(THREADS)
void fakequant_rowwise(const float* __restrict__ x, float* __restrict__ out) {
    const int row = blockIdx.x;
    const size_t base = (size_t)row * N_COLS;
    const float4* __restrict__ xrow = reinterpret_cast<const float4*>(x + base);
    float4* __restrict__ orow = reinterpret_cast<float4*>(out + base);
    const int t = threadIdx.x;

    // ---- pass 1: load into registers (coalesced float4), local min/max ----
    float4 v[VPT];
    float vmin = 0.0f;   // reference clamps min to <= 0
    float vmax = 0.0f;   // reference clamps max to >= 0
#pragma unroll
    for (int i = 0; i < VPT; ++i) {
        v[i] = xrow[i * THREADS + t];
        vmin = fminf(vmin, fminf(fminf(v[i].x, v[i].y), fminf(v[i].z, v[i].w)));
        vmax = fmaxf(vmax, fmaxf(fmaxf(v[i].x, v[i].y), fmaxf(v[i].z, v[i].w)));
    }

    // ---- wave-level butterfly reduce (64 lanes) ----
#pragma unroll
    for (int off = 32; off >= 1; off >>= 1) {
        vmin = fminf(vmin, __shfl_xor(vmin, off, 64));
        vmax = fmaxf(vmax, __shfl_xor(vmax, off, 64));
    }

    // ---- cross-wave reduce via tiny LDS; every thread computes redundantly ----
    __shared__ float smin[N_WAVES], smax[N_WAVES];
    const int wid = t >> 6;
    if ((t & 63) == 0) { smin[wid] = vmin; smax[wid] = vmax; }
    __syncthreads();
#pragma unroll
    for (int w = 0; w < N_WAVES; ++w) {
        vmin = fminf(vmin, smin[w]);
        vmax = fmaxf(vmax, smax[w]);
    }

    // ---- per-row quant params (match reference arithmetic) ----
    const float scale = fmaxf((vmax - vmin) / LEVELS_F, EPS);
    const float zero  = rintf(-vmin / scale);        // round-half-even == jnp.round
    const float inv_scale = 1.0f / scale;

    // ---- pass 2: quantize registers, store coalesced float4 ----
#pragma unroll
    for (int i = 0; i < VPT; ++i) {
        float4 o;
        {
            float q = fminf(fmaxf(rintf(v[i].x * inv_scale) + zero, 0.0f), LEVELS_F);
            o.x = (q - zero) * scale;
        }
        {
            float q = fminf(fmaxf(rintf(v[i].y * inv_scale) + zero, 0.0f), LEVELS_F);
            o.y = (q - zero) * scale;
        }
        {
            float q = fminf(fmaxf(rintf(v[i].z * inv_scale) + zero, 0.0f), LEVELS_F);
            o.z = (q - zero) * scale;
        }
        {
            float q = fminf(fmaxf(rintf(v[i].w * inv_scale) + zero, 0.0f), LEVELS_F);
            o.w = (q - zero) * scale;
        }
        orow[i * THREADS + t] = o;
    }
}

extern "C" void kernel_launch(void* const* d_in, const int* in_sizes, int n_in,
                              void* d_out, int out_size, void* d_ws, size_t ws_size,
                              hipStream_t stream) {
    const float* x = (const float*)d_in[0];
    float* out = (float*)d_out;
    const int rows = in_sizes[0] / N_COLS;   // 4096
    fakequant_rowwise<<<rows, THREADS, 0, stream>>>(x, out);
}

// Round 3
// 94.289 us; speedup vs baseline: 1.1201x; 1.1201x over previous
//
#include <hip/hip_runtime.h>

// Per-channel (row) asymmetric min-max fake quantization.
// x: [C=4096, N=16384] fp32. One block per row; data held in registers
// between the min/max pass and the quantize pass (single HBM read).
// Streaming (nontemporal) loads/stores: zero reuse -> skip L2/L3 allocation.

constexpr int N_COLS = 16384;
constexpr int THREADS = 512;                       // 8 waves
constexpr int N_WAVES = THREADS / 64;
constexpr int VPT = N_COLS / 4 / THREADS;          // float4 per thread = 8
constexpr float LEVELS_F = 255.0f;
constexpr float EPS = 1e-8f;

// clang ext_vector type: accepted by __builtin_nontemporal_{load,store}
// (HIP_vector_type<float,4> is a class and is rejected).
typedef float f32x4 __attribute__((ext_vector_type(4)));

__global__ __launch_bounds__(THREADS)
void fakequant_rowwise(const float* __restrict__ x, float* __restrict__ out) {
    const int row = blockIdx.x;
    const size_t base = (size_t)row * N_COLS;
    const f32x4* __restrict__ xrow = reinterpret_cast<const f32x4*>(x + base);
    f32x4* __restrict__ orow = reinterpret_cast<f32x4*>(out + base);
    const int t = threadIdx.x;

    // ---- pass 1: load into registers (coalesced 16B, nontemporal) ----
    f32x4 v[VPT];
    float vmin = 0.0f;   // reference clamps min to <= 0
    float vmax = 0.0f;   // reference clamps max to >= 0
#pragma unroll
    for (int i = 0; i < VPT; ++i) {
        v[i] = __builtin_nontemporal_load(&xrow[i * THREADS + t]);
        vmin = fminf(vmin, fminf(fminf(v[i].x, v[i].y), fminf(v[i].z, v[i].w)));
        vmax = fmaxf(vmax, fmaxf(fmaxf(v[i].x, v[i].y), fmaxf(v[i].z, v[i].w)));
    }

    // ---- wave-level butterfly reduce (64 lanes) ----
#pragma unroll
    for (int off = 32; off >= 1; off >>= 1) {
        vmin = fminf(vmin, __shfl_xor(vmin, off, 64));
        vmax = fmaxf(vmax, __shfl_xor(vmax, off, 64));
    }

    // ---- cross-wave reduce via tiny LDS; every thread computes redundantly ----
    __shared__ float smin[N_WAVES], smax[N_WAVES];
    const int wid = t >> 6;
    if ((t & 63) == 0) { smin[wid] = vmin; smax[wid] = vmax; }
    __syncthreads();
#pragma unroll
    for (int w = 0; w < N_WAVES; ++w) {
        vmin = fminf(vmin, smin[w]);
        vmax = fmaxf(vmax, smax[w]);
    }

    // ---- per-row quant params (match reference arithmetic) ----
    const float scale = fmaxf((vmax - vmin) / LEVELS_F, EPS);
    const float zero  = rintf(-vmin / scale);        // round-half-even == jnp.round
    const float inv_scale = 1.0f / scale;

    // ---- pass 2: quantize registers, store coalesced 16B (nontemporal) ----
#pragma unroll
    for (int i = 0; i < VPT; ++i) {
        f32x4 o;
        {
            float q = fminf(fmaxf(rintf(v[i].x * inv_scale) + zero, 0.0f), LEVELS_F);
            o.x = (q - zero) * scale;
        }
        {
            float q = fminf(fmaxf(rintf(v[i].y * inv_scale) + zero, 0.0f), LEVELS_F);
            o.y = (q - zero) * scale;
        }
        {
            float q = fminf(fmaxf(rintf(v[i].z * inv_scale) + zero, 0.0f), LEVELS_F);
            o.z = (q - zero) * scale;
        }
        {
            float q = fminf(fmaxf(rintf(v[i].w * inv_scale) + zero, 0.0f), LEVELS_F);
            o.w = (q - zero) * scale;
        }
        __builtin_nontemporal_store(o, &orow[i * THREADS + t]);
    }
}

extern "C" void kernel_launch(void* const* d_in, const int* in_sizes, int n_in,
                              void* d_out, int out_size, void* d_ws, size_t ws_size,
                              hipStream_t stream) {
    const float* x = (const float*)d_in[0];
    float* out = (float*)d_out;
    const int rows = in_sizes[0] / N_COLS;   // 4096
    fakequant_rowwise<<<rows, THREADS, 0, stream>>>(x, out);
}

// Round 4
// 92.822 us; speedup vs baseline: 1.1379x; 1.0158x over previous
//
#include <hip/hip_runtime.h>

// Per-channel (row) asymmetric min-max fake quantization.
// x: [C=4096, N=16384] fp32. One block per row; data held in registers
// between the min/max pass and the quantize pass (single HBM read).
// Streaming (nontemporal) loads/stores: zero reuse -> skip L2/L3 allocation.
// __launch_bounds__(512, 8): cap VGPR at 64 -> 4 blocks/CU co-resident,
// so read-phase and write-phase of different blocks interleave at the CU.

constexpr int N_COLS = 16384;
constexpr int THREADS = 512;                       // 8 waves
constexpr int N_WAVES = THREADS / 64;
constexpr int VPT = N_COLS / 4 / THREADS;          // float4 per thread = 8
constexpr float LEVELS_F = 255.0f;
constexpr float EPS = 1e-8f;

// clang ext_vector type: accepted by __builtin_nontemporal_{load,store}
// (HIP_vector_type<float,4> is a class and is rejected).
typedef float f32x4 __attribute__((ext_vector_type(4)));

__global__ __launch_bounds__(THREADS, 8)
void fakequant_rowwise(const float* __restrict__ x, float* __restrict__ out) {
    const int row = blockIdx.x;
    const size_t base = (size_t)row * N_COLS;
    const f32x4* __restrict__ xrow = reinterpret_cast<const f32x4*>(x + base);
    f32x4* __restrict__ orow = reinterpret_cast<f32x4*>(out + base);
    const int t = threadIdx.x;

    // ---- pass 1: issue ALL loads first (max memory-level parallelism) ----
    f32x4 v[VPT];
#pragma unroll
    for (int i = 0; i < VPT; ++i) {
        v[i] = __builtin_nontemporal_load(&xrow[i * THREADS + t]);
    }

    // ---- then reduce (waits drain newest-to-oldest as values are consumed) ----
    float vmin = 0.0f;   // reference clamps min to <= 0
    float vmax = 0.0f;   // reference clamps max to >= 0
#pragma unroll
    for (int i = 0; i < VPT; ++i) {
        vmin = fminf(vmin, fminf(fminf(v[i].x, v[i].y), fminf(v[i].z, v[i].w)));
        vmax = fmaxf(vmax, fmaxf(fmaxf(v[i].x, v[i].y), fmaxf(v[i].z, v[i].w)));
    }

    // ---- wave-level butterfly reduce (64 lanes) ----
#pragma unroll
    for (int off = 32; off >= 1; off >>= 1) {
        vmin = fminf(vmin, __shfl_xor(vmin, off, 64));
        vmax = fmaxf(vmax, __shfl_xor(vmax, off, 64));
    }

    // ---- cross-wave reduce via tiny LDS; every thread computes redundantly ----
    __shared__ float smin[N_WAVES], smax[N_WAVES];
    const int wid = t >> 6;
    if ((t & 63) == 0) { smin[wid] = vmin; smax[wid] = vmax; }
    __syncthreads();
#pragma unroll
    for (int w = 0; w < N_WAVES; ++w) {
        vmin = fminf(vmin, smin[w]);
        vmax = fmaxf(vmax, smax[w]);
    }

    // ---- per-row quant params (match reference arithmetic) ----
    const float scale = fmaxf((vmax - vmin) / LEVELS_F, EPS);
    const float zero  = rintf(-vmin / scale);        // round-half-even == jnp.round
    const float inv_scale = 1.0f / scale;

    // ---- pass 2: quantize registers, store coalesced 16B (nontemporal) ----
#pragma unroll
    for (int i = 0; i < VPT; ++i) {
        f32x4 o;
        {
            float q = fminf(fmaxf(rintf(v[i].x * inv_scale) + zero, 0.0f), LEVELS_F);
            o.x = (q - zero) * scale;
        }
        {
            float q = fminf(fmaxf(rintf(v[i].y * inv_scale) + zero, 0.0f), LEVELS_F);
            o.y = (q - zero) * scale;
        }
        {
            float q = fminf(fmaxf(rintf(v[i].z * inv_scale) + zero, 0.0f), LEVELS_F);
            o.z = (q - zero) * scale;
        }
        {
            float q = fminf(fmaxf(rintf(v[i].w * inv_scale) + zero, 0.0f), LEVELS_F);
            o.w = (q - zero) * scale;
        }
        __builtin_nontemporal_store(o, &orow[i * THREADS + t]);
    }
}

extern "C" void kernel_launch(void* const* d_in, const int* in_sizes, int n_in,
                              void* d_out, int out_size, void* d_ws, size_t ws_size,
                              hipStream_t stream) {
    const float* x = (const float*)d_in[0];
    float* out = (float*)d_out;
    const int rows = in_sizes[0] / N_COLS;   // 4096
    fakequant_rowwise<<<rows, THREADS, 0, stream>>>(x, out);
}